// Round 7
// baseline (251.215 us; speedup 1.0000x reference)
//
#include <hip/hip_runtime.h>

typedef __bf16 bf16x8 __attribute__((ext_vector_type(8)));
typedef __bf16 bf16x4 __attribute__((ext_vector_type(4)));
typedef float  f32x4  __attribute__((ext_vector_type(4)));

#define B_    4
#define S_    2048
#define E_    1024
#define H_    16
#define D_    64
#define MROWS (B_*S_)   // 8192

// log2(e) / sqrt(D) — folded into Q in the GEMM epilogue
#define SCORE_SCALE 0.18033688011112043f

__device__ __forceinline__ void load_lds16(const void* g, void* l) {
  __builtin_amdgcn_global_load_lds((__attribute__((address_space(1))) void*)g,
                                   (__attribute__((address_space(3))) void*)l,
                                   16, 0, 0);
}

__device__ __forceinline__ f32x4 mfma16(bf16x8 a, bf16x8 b, f32x4 c) {
  return __builtin_amdgcn_mfma_f32_16x16x32_bf16(a, b, c, 0, 0, 0);
}

// swizzled LDS element offset, 64-col bf16 rows: data chunk (8 elems) lands at
// physical chunk (dchunk ^ (row&7))  -> all fragment reads are <=2-way (free)
__device__ __forceinline__ int swz(int row, int dchunk) {
  return row * 64 + ((dchunk ^ (row & 7)) * 8);
}

// ---------------- fused prep: cvt_x | pack_w | pack_wo ----------------

__global__ void prep(const float4* __restrict__ x, const float* __restrict__ Wq,
                     const float* __restrict__ Wk, const float* __restrict__ Wv,
                     const float* __restrict__ bq, const float* __restrict__ bk,
                     const float* __restrict__ bv, const float* __restrict__ Wo,
                     __bf16* __restrict__ xb, __bf16* __restrict__ Wt,
                     float* __restrict__ bqkv, __bf16* __restrict__ Wot) {
  __shared__ float t[64][65];
  int bid = blockIdx.x;
  if (bid < 8192) {                      // cvt_x: fp32 x -> bf16
    int id = bid * 256 + threadIdx.x;
    float4 v = x[id];
    bf16x4 o = { (__bf16)v.x, (__bf16)v.y, (__bf16)v.z, (__bf16)v.w };
    *(bf16x4*)(xb + 4 * (size_t)id) = o;
    return;
  }
  int tx = threadIdx.x & 63;
  int ty = threadIdx.x >> 6;
  if (bid < 8960) {                      // pack_w: [H,E,D] -> Wt[3*H*D][E]
    int b2 = bid - 8192;                 // 768
    int e0 = (b2 & 15) * 64;
    int h  = (b2 >> 4) & 15;
    int p  = b2 >> 8;
    const float* W    = (p == 0) ? Wq : (p == 1) ? Wk : Wv;
    const float* bsrc = (p == 0) ? bq : (p == 1) ? bk : bv;
#pragma unroll
    for (int r = 0; r < 16; ++r) {
      int eL = ty + r * 4;
      t[eL][tx] = W[((size_t)h * 1024 + (e0 + eL)) * 64 + tx];
    }
    __syncthreads();
#pragma unroll
    for (int r = 0; r < 16; ++r) {
      int d = ty + r * 4;
      Wt[((size_t)(p * 1024 + h * 64 + d)) * 1024 + e0 + tx] = (__bf16)t[tx][d];
    }
    if ((b2 & 15) == 0 && threadIdx.x < 64)
      bqkv[p * 1024 + h * 64 + threadIdx.x] = bsrc[h * 64 + threadIdx.x];
  } else {                               // pack_wo: Wo[1024,1024] -> Wot[e][hd]
    int b2 = bid - 8960;                 // 256
    int hd0 = (b2 >> 4) * 64;
    int e0  = (b2 & 15) * 64;
#pragma unroll
    for (int r = 0; r < 16; ++r) {
      int hdL = ty + r * 4;
      t[hdL][tx] = Wo[(size_t)(hd0 + hdL) * 1024 + e0 + tx];
    }
    __syncthreads();
#pragma unroll
    for (int r = 0; r < 16; ++r) {
      int eL = ty + r * 4;
      Wot[(size_t)(e0 + eL) * 1024 + hd0 + tx] = (__bf16)t[tx][eL];
    }
  }
}

// ------- 8-phase GEMM, BM=128 for 2 blocks/CU: C = A @ Bt^T + bias ----------
// (R6-proven: MODE1 dropped from 66 -> <64 us with this residency config.)
// BM=128 x BN (192 MODE1 | 128 MODE0), BK=64, K=1024 (16 K-tiles, 2/iter).
// 512 thr = 8 waves (2M x 4N); per-wave 64 x BN/4; acc[4][NB] f32x4.
// LDS/block = 80 KB (NB3) / 64 KB (NB2) -> 2 independent blocks per CU.

template <int MODE, int BN, int NDIM>
__global__ __launch_bounds__(512, 4) void gemm8h(const __bf16* __restrict__ A,
                                                 const __bf16* __restrict__ Bt,
                                                 const float* __restrict__ bias,
                                                 void* __restrict__ Cout,
                                                 __bf16* __restrict__ VT) {
  constexpr int K = 1024;
  constexpr int NB = BN / 64;            // B sub-tiles (and N frags per wave)
  constexpr int WC = BN / 4;             // per-wave col span
  __shared__ __attribute__((aligned(16))) __bf16 As[2 * 128 * 64];
  __shared__ __attribute__((aligned(16))) __bf16 Bs[2 * BN * 64];

  int tid = threadIdx.x, wave = tid >> 6, lane = tid & 63;
  int quad = lane >> 4, cc = lane & 15;
  constexpr int nb = NDIM / BN;
  int nwg = (int)gridDim.x;
  int bid = (int)blockIdx.x;
  bid = (bid & 7) * (nwg >> 3) + (bid >> 3);   // XCD-bijective (nwg%8==0)
  int bm = bid / nb, bn = bid % nb;
  const __bf16* Abase = A + (size_t)bm * 128 * K;
  const __bf16* Bbase = Bt + (size_t)bn * BN * K;
  int wrow = (wave >> 2) * 64;
  int wcol = (wave & 3) * WC;

  f32x4 acc[4][NB];
#pragma unroll
  for (int m = 0; m < 4; ++m)
#pragma unroll
    for (int n = 0; n < NB; ++n) acc[m][n] = (f32x4){0.f, 0.f, 0.f, 0.f};

  int srl = tid >> 3;                    // staging row 0..63
  int sch = tid & 7;
  int scol = (sch ^ (srl & 7)) * 8;      // pre-swizzled source col

#define STAGE_A(t, sub, buf)                                                   \
  load_lds16(Abase + (size_t)((sub) * 64 + srl) * K + (t) * 64 + scol,         \
             &As[(buf) * 8192 + (sub) * 4096 + tid * 8])
#define STAGE_B(t, sub, buf)                                                   \
  load_lds16(Bbase + (size_t)((sub) * 64 + srl) * K + (t) * 64 + scol,         \
             &Bs[(buf) * (BN * 64) + (sub) * 4096 + tid * 8])

  // prologue: tile0 full (2+NB), tile1 A pair; vmcnt(2) -> tile0 landed
#pragma unroll
  for (int s = 0; s < 2; ++s) STAGE_A(0, s, 0);
#pragma unroll
  for (int s = 0; s < NB; ++s) STAGE_B(0, s, 0);
#pragma unroll
  for (int s = 0; s < 2; ++s) STAGE_A(1, s, 1);
  asm volatile("s_waitcnt vmcnt(2)" ::: "memory");
  __builtin_amdgcn_sched_barrier(0);
  asm volatile("s_barrier" ::: "memory");

  bf16x8 af[4][2], bfr[NB][2];

#define RD_B(buf)                                                              \
  _Pragma("unroll") for (int n = 0; n < NB; ++n)                               \
      _Pragma("unroll") for (int kk = 0; kk < 2; ++kk)                         \
          bfr[n][kk] = *(const bf16x8*)&Bs[(buf) * (BN * 64) +                 \
                                           swz(wcol + n * 16 + cc, kk * 4 + quad)]
#define RD_A2(buf, mlo)                                                        \
  _Pragma("unroll") for (int m = mlo; m < (mlo) + 2; ++m)                      \
      _Pragma("unroll") for (int kk = 0; kk < 2; ++kk)                         \
          af[m][kk] = *(const bf16x8*)&As[(buf) * 8192 +                       \
                                          swz(wrow + m * 16 + cc, kk * 4 + quad)]
#define MFMA_M(m)                                                              \
  do {                                                                         \
    __builtin_amdgcn_s_setprio(1);                                             \
    _Pragma("unroll") for (int n = 0; n < NB; ++n)                             \
        _Pragma("unroll") for (int kk = 0; kk < 2; ++kk)                       \
            acc[m][n] = mfma16(af[m][kk], bfr[n][kk], acc[m][n]);              \
    __builtin_amdgcn_s_setprio(0);                                             \
  } while (0)
#define LGKM0                                                                  \
  asm volatile("s_waitcnt lgkmcnt(0)" ::: "memory");                           \
  __builtin_amdgcn_sched_barrier(0)
#define VMC2                                                                   \
  asm volatile("s_waitcnt vmcnt(2)" ::: "memory");                             \
  __builtin_amdgcn_sched_barrier(0)
#define BAR asm volatile("s_barrier" ::: "memory")

#pragma unroll 1
  for (int it = 0; it < 8; ++it) {
    int b_t = 2 * it + 1;
    int c_t = (2 * it + 2) & 15;         // clamped: dead restage on last iter
    int d_t = (2 * it + 3) & 15;
    // ---- tile a (buf0) ----
    RD_B(0); RD_A2(0, 0);
    STAGE_B(b_t, 0, 1); STAGE_B(b_t, 1, 1);
    LGKM0; MFMA_M(0); BAR;
    RD_A2(0, 2);
    if (NB >= 3) STAGE_B(b_t, 2, 1);
    LGKM0; MFMA_M(1); BAR;
    STAGE_A(c_t, 0, 0); STAGE_A(c_t, 1, 0);
    MFMA_M(2); BAR;
    MFMA_M(3);
    VMC2; BAR;
    // ---- tile b (buf1) ----
    RD_B(1); RD_A2(1, 0);
    STAGE_B(c_t, 0, 0); STAGE_B(c_t, 1, 0);
    LGKM0; MFMA_M(0); BAR;
    RD_A2(1, 2);
    if (NB >= 3) STAGE_B(c_t, 2, 0);
    LGKM0; MFMA_M(1); BAR;
    STAGE_A(d_t, 0, 1); STAGE_A(d_t, 1, 1);
    MFMA_M(2); BAR;
    MFMA_M(3);
    VMC2; BAR;
  }
  asm volatile("s_waitcnt vmcnt(0)" ::: "memory");  // drain dead restages

  // epilogue — plain cached stores (nt falsified in R5)
#pragma unroll
  for (int n = 0; n < NB; ++n) {
    int gcol = bn * BN + wcol + n * 16 + cc;
    float bv = bias[gcol];
#pragma unroll
    for (int m = 0; m < 4; ++m) {
      int grow0 = bm * 128 + wrow + m * 16 + quad * 4;
      if (MODE == 0) {
#pragma unroll
        for (int r = 0; r < 4; ++r)
          ((float*)Cout)[(size_t)(grow0 + r) * NDIM + gcol] = acc[m][n][r] + bv;
      } else if (gcol < 2048) {          // Q|K -> QKb (stride 2048), Q scaled
        float sc = (gcol < 1024) ? SCORE_SCALE : 1.0f;
#pragma unroll
        for (int r = 0; r < 4; ++r)
          ((__bf16*)Cout)[(size_t)(grow0 + r) * 2048 + gcol] =
              (__bf16)((acc[m][n][r] + bv) * sc);
      } else {                           // V -> VT[(b*16+h)*64+d][s], packed x4
        int bh = (grow0 >> 11) * 16 + ((gcol >> 6) & 15);
        int d  = gcol & 63;
        bf16x4 pk;
#pragma unroll
        for (int r = 0; r < 4; ++r) pk[r] = (__bf16)(acc[m][n][r] + bv);
        *(bf16x4*)&VT[((size_t)(bh * 64 + d)) * 2048 + (grow0 & 2047)] = pk;
      }
    }
  }
#undef STAGE_A
#undef STAGE_B
#undef RD_B
#undef RD_A2
#undef MFMA_M
#undef LGKM0
#undef VMC2
#undef BAR
}

// ---------------- causal flash attention — paired q-tiles -------------------
// 512 blocks, 512 thr (8 waves). Block g|bh handles q-tile PAIR (15-g, g):
// waves 0-3 own heavy tile rows (q0h + w*32), waves 4-7 light (q0l + (w-4)*32).
// EVERY block has exactly 34 tile-units of compute (2(15-g)+2 + 2g+2) and
// 136 wave-tile MFMA units -> any block->CU assignment is compute-balanced.
// KV staged ONCE per pair (was twice), one 512-thread pass per tile.
// LDS 64 KB: Qs 32K (overlaid by 8x2K per-wave Ps after prologue) | Ks 2x8K |
// Vs 2x8K -> 2 blocks/CU, grid 512 = ALL blocks resident, zero refill tail,
// 16 waves/CU (50% cap vs old 37.5%). Inner per-wave code unchanged from R1.

__global__ __launch_bounds__(512, 4) void attn(const __bf16* __restrict__ QKb,
                                               const __bf16* __restrict__ VT,
                                               __bf16* __restrict__ O) {
  int bx = blockIdx.x;
  int bh = bx & 63;
  int g  = bx >> 6;                           // 0..7
  int qth = 15 - g;                           // heavy tile (waves 0-3)
  int qtl = g;                                // light tile (waves 4-7)
  int h  = bh & 15;
  int b  = bh >> 4;
  int q0h = qth * 128, q0l = qtl * 128;
  int tid = threadIdx.x, wave = tid >> 6, lane = tid & 63;
  int quad = lane >> 4, c = lane & 15;

  __shared__ __attribute__((aligned(16))) __bf16 smem[32768];
  __bf16* Qs = smem;                         // 256*64 (heavy 0-127 | light 128-255)
  __bf16* Ks = smem + 16384;                 // 2 * 64*64
  __bf16* Vs = smem + 24576;                 // 2 * 64*64 (V^T tiles [d][kv])
  __bf16* Ps = smem + wave * 2048;           // own wave's Q rows (dead after prologue)

  const __bf16* Qbh = QKb + (size_t)(b * S_ + q0h) * 2048 + h * 64;
  const __bf16* Qbl = QKb + (size_t)(b * S_ + q0l) * 2048 + h * 64;
  const __bf16* Vbase = VT + (size_t)bh * (64 * 2048);
#pragma unroll
  for (int p = 0; p < 4; ++p) {
    int gi = tid + p * 512;           // 0..2047 ; p<2 -> heavy rows, else light
    int row = gi >> 3, pch = gi & 7;
    const __bf16* base = (p < 2) ? Qbh : Qbl;
    load_lds16(base + (size_t)(row & 127) * 2048 + (pch ^ (row & 7)) * 8,
               &Qs[gi * 8]);
  }
  {
    const __bf16* Kb = QKb + (size_t)(b * S_) * 2048 + 1024 + h * 64;
    int row = tid >> 3, pch = tid & 7;
    load_lds16(Kb + (size_t)row * 2048 + (pch ^ (row & 7)) * 8, &Ks[tid * 8]);
    load_lds16(Vbase + (size_t)row * 2048 + (pch ^ (row & 7)) * 8, &Vs[tid * 8]);
  }
  __syncthreads();

  bf16x8 qf[2][2];
#pragma unroll
  for (int i = 0; i < 2; ++i)
#pragma unroll
    for (int kk = 0; kk < 2; ++kk)
      qf[i][kk] = *(const bf16x8*)&Qs[swz(wave * 32 + i * 16 + c, kk * 4 + quad)];

  const __bf16 one_b = (__bf16)1.0f;
  bf16x8 ones = { one_b, one_b, one_b, one_b, one_b, one_b, one_b, one_b };

  f32x4 acc_o[2][4], acc_l[2];
#pragma unroll
  for (int i = 0; i < 2; ++i) {
    acc_l[i] = (f32x4){0.f, 0.f, 0.f, 0.f};
#pragma unroll
    for (int j = 0; j < 4; ++j) acc_o[i][j] = (f32x4){0.f, 0.f, 0.f, 0.f};
  }

  // this wave's first q row (heavy waves -> q0h tile, light -> q0l tile)
  int qwave = (wave < 4) ? (q0h + wave * 32) : (q0l + (wave - 4) * 32);
  int ntiles = qth * 2 + 2;
  for (int t = 0; t < ntiles; ++t) {
    int cur = t & 1;
    if (t + 1 < ntiles) {             // prefetch next KV tile (other buffer)
      int kv1 = (t + 1) * 64;
      const __bf16* Kb = QKb + (size_t)(b * S_ + kv1) * 2048 + 1024 + h * 64;
      const __bf16* Vb = Vbase + kv1;
      int row = tid >> 3, pch = tid & 7;
      load_lds16(Kb + (size_t)row * 2048 + (pch ^ (row & 7)) * 8,
                 &Ks[(cur ^ 1) * 4096 + tid * 8]);
      load_lds16(Vb + (size_t)row * 2048 + (pch ^ (row & 7)) * 8,
                 &Vs[(cur ^ 1) * 4096 + tid * 8]);
    }

    int kv0 = t * 64;
    if (kv0 <= qwave + 31) {          // wave has at least one unmasked row
      const __bf16* Kc = Ks + cur * 4096;
      const __bf16* Vc = Vs + cur * 4096;

      // S^T = K Q^T : rows=kv, cols=q  (log2-domain scores, Q pre-scaled)
      f32x4 acc_t[2][4];
#pragma unroll
      for (int i = 0; i < 2; ++i)
#pragma unroll
        for (int j = 0; j < 4; ++j) acc_t[i][j] = (f32x4){0.f, 0.f, 0.f, 0.f};
      bf16x8 kf[4][2];
#pragma unroll
      for (int j = 0; j < 4; ++j)
#pragma unroll
        for (int kk = 0; kk < 2; ++kk)
          kf[j][kk] = *(const bf16x8*)&Kc[swz(j * 16 + c, kk * 4 + quad)];
      __builtin_amdgcn_s_setprio(1);
#pragma unroll
      for (int i = 0; i < 2; ++i)
#pragma unroll
        for (int j = 0; j < 4; ++j)
#pragma unroll
          for (int kk = 0; kk < 2; ++kk)
            acc_t[i][j] = mfma16(kf[j][kk], qf[i][kk], acc_t[i][j]);
      __builtin_amdgcn_s_setprio(0);

      // p = exp2(s); mask only when this wave straddles the diagonal
      bool domask = (kv0 + 63 > qwave);
#pragma unroll
      for (int i = 0; i < 2; ++i) {
        int q_l = i * 16 + c;                      // wave-local q row
        int q_g = qwave + q_l;                     // global q row
#pragma unroll
        for (int j = 0; j < 4; ++j) {
          bf16x4 pk;
#pragma unroll
          for (int r = 0; r < 4; ++r) {
            float p = __builtin_amdgcn_exp2f(acc_t[i][j][r]);
            if (domask) {
              int kv = kv0 + j * 16 + quad * 4 + r;
              p = (kv > q_g) ? 0.f : p;
            }
            pk[r] = (__bf16)p;
          }
          int dch8 = j * 2 + (quad >> 1);
          int phys = q_l * 64 + ((dch8 ^ (q_l & 7)) * 8) + (quad & 1) * 4;
          *(bf16x4*)&Ps[phys] = pk;
        }
      }

      // PV + row-sum (ones-MFMA); same-wave LDS ops are in-order
      bf16x8 pf[2][2], vf[4][2];
#pragma unroll
      for (int i = 0; i < 2; ++i)
#pragma unroll
        for (int kk = 0; kk < 2; ++kk)
          pf[i][kk] = *(const bf16x8*)&Ps[swz(i * 16 + c, kk * 4 + quad)];
#pragma unroll
      for (int j = 0; j < 4; ++j)
#pragma unroll
        for (int kk = 0; kk < 2; ++kk)
          vf[j][kk] = *(const bf16x8*)&Vc[swz(j * 16 + c, kk * 4 + quad)];
      __builtin_amdgcn_s_setprio(1);
#pragma unroll
      for (int i = 0; i < 2; ++i) {
#pragma unroll
        for (int j = 0; j < 4; ++j)
#pragma unroll
          for (int kk = 0; kk < 2; ++kk)
            acc_o[i][j] = mfma16(pf[i][kk], vf[j][kk], acc_o[i][j]);
        acc_l[i] = mfma16(pf[i][0], ones, acc_l[i]);
        acc_l[i] = mfma16(pf[i][1], ones, acc_l[i]);
      }
      __builtin_amdgcn_s_setprio(0);
    }

    __syncthreads();   // staging for t+1 complete; buf (cur) free for t+2
  }

  __bf16* Obase = O + (size_t)(b * S_ + qwave) * 1024 + h * 64;
#pragma unroll
  for (int i = 0; i < 2; ++i)
#pragma unroll
    for (int r = 0; r < 4; ++r) {
      float rl = 1.0f / acc_l[i][r];
      int row = i * 16 + quad * 4 + r;           // wave-local 0..31
#pragma unroll
      for (int j = 0; j < 4; ++j)
        Obase[(size_t)row * 1024 + j * 16 + c] = (__bf16)(acc_o[i][j][r] * rl);
    }
}

// ---------------- launcher ----------------

extern "C" void kernel_launch(void* const* d_in, const int* in_sizes, int n_in,
                              void* d_out, int out_size, void* d_ws, size_t ws_size,
                              hipStream_t stream) {
  (void)in_sizes; (void)n_in; (void)out_size; (void)ws_size;
  const float* x  = (const float*)d_in[0];
  const float* Wq = (const float*)d_in[1];
  const float* bq = (const float*)d_in[2];
  const float* Wk = (const float*)d_in[3];
  const float* bk = (const float*)d_in[4];
  const float* Wv = (const float*)d_in[5];
  const float* bv = (const float*)d_in[6];
  const float* Wo = (const float*)d_in[7];
  const float* bo = (const float*)d_in[8];

  char* w = (char*)d_ws;
  __bf16* xb   = (__bf16*)(w);                         // 16 MB
  __bf16* Wt   = (__bf16*)(w + (16ull << 20));         //  6 MB
  __bf16* Wot  = (__bf16*)(w + (22ull << 20));         //  2 MB
  float*  bqkv = (float*) (w + (24ull << 20));         // 12 KB
  __bf16* QKb  = (__bf16*)(w + (25ull << 20));         // 32 MB (Q|K, stride 2048)
  __bf16* Ob   = (__bf16*)(w + (57ull << 20));         // 16 MB
  __bf16* VT   = (__bf16*)(w + (73ull << 20));         // 16 MB (total 89 MB)

  prep<<<9216, 256, 0, stream>>>((const float4*)x, Wq, Wk, Wv, bq, bk, bv, Wo,
                                 xb, Wt, bqkv, Wot);
  gemm8h<1, 192, 3072><<<1024, 512, 0, stream>>>(xb, Wt, bqkv, (void*)QKb, VT);
  attn<<<512, 512, 0, stream>>>(QKb, VT, Ob);
  gemm8h<0, 128, 1024><<<512, 512, 0, stream>>>(Ob, Wot, bo, d_out, nullptr);
}

// Round 8
// 245.436 us; speedup vs baseline: 1.0235x; 1.0235x over previous
//
#include <hip/hip_runtime.h>

typedef __bf16 bf16x8 __attribute__((ext_vector_type(8)));
typedef __bf16 bf16x4 __attribute__((ext_vector_type(4)));
typedef float  f32x4  __attribute__((ext_vector_type(4)));

#define B_    4
#define S_    2048
#define E_    1024
#define H_    16
#define D_    64
#define MROWS (B_*S_)   // 8192

// log2(e) / sqrt(D) — folded into Q in the GEMM epilogue
#define SCORE_SCALE 0.18033688011112043f

__device__ __forceinline__ void load_lds16(const void* g, void* l) {
  __builtin_amdgcn_global_load_lds((__attribute__((address_space(1))) void*)g,
                                   (__attribute__((address_space(3))) void*)l,
                                   16, 0, 0);
}

__device__ __forceinline__ f32x4 mfma16(bf16x8 a, bf16x8 b, f32x4 c) {
  return __builtin_amdgcn_mfma_f32_16x16x32_bf16(a, b, c, 0, 0, 0);
}

// swizzled LDS element offset, 64-col bf16 rows: data chunk (8 elems) lands at
// physical chunk (dchunk ^ (row&7))  -> all fragment reads are <=2-way (free)
__device__ __forceinline__ int swz(int row, int dchunk) {
  return row * 64 + ((dchunk ^ (row & 7)) * 8);
}

// ---------------- fused prep: cvt_x | pack_w | pack_wo ----------------

__global__ void prep(const float4* __restrict__ x, const float* __restrict__ Wq,
                     const float* __restrict__ Wk, const float* __restrict__ Wv,
                     const float* __restrict__ bq, const float* __restrict__ bk,
                     const float* __restrict__ bv, const float* __restrict__ Wo,
                     __bf16* __restrict__ xb, __bf16* __restrict__ Wt,
                     float* __restrict__ bqkv, __bf16* __restrict__ Wot) {
  __shared__ float t[64][65];
  int bid = blockIdx.x;
  if (bid < 8192) {                      // cvt_x: fp32 x -> bf16
    int id = bid * 256 + threadIdx.x;
    float4 v = x[id];
    bf16x4 o = { (__bf16)v.x, (__bf16)v.y, (__bf16)v.z, (__bf16)v.w };
    *(bf16x4*)(xb + 4 * (size_t)id) = o;
    return;
  }
  int tx = threadIdx.x & 63;
  int ty = threadIdx.x >> 6;
  if (bid < 8960) {                      // pack_w: [H,E,D] -> Wt[3*H*D][E]
    int b2 = bid - 8192;                 // 768
    int e0 = (b2 & 15) * 64;
    int h  = (b2 >> 4) & 15;
    int p  = b2 >> 8;
    const float* W    = (p == 0) ? Wq : (p == 1) ? Wk : Wv;
    const float* bsrc = (p == 0) ? bq : (p == 1) ? bk : bv;
#pragma unroll
    for (int r = 0; r < 16; ++r) {
      int eL = ty + r * 4;
      t[eL][tx] = W[((size_t)h * 1024 + (e0 + eL)) * 64 + tx];
    }
    __syncthreads();
#pragma unroll
    for (int r = 0; r < 16; ++r) {
      int d = ty + r * 4;
      Wt[((size_t)(p * 1024 + h * 64 + d)) * 1024 + e0 + tx] = (__bf16)t[tx][d];
    }
    if ((b2 & 15) == 0 && threadIdx.x < 64)
      bqkv[p * 1024 + h * 64 + threadIdx.x] = bsrc[h * 64 + threadIdx.x];
  } else {                               // pack_wo: Wo[1024,1024] -> Wot[e][hd]
    int b2 = bid - 8960;                 // 256
    int hd0 = (b2 >> 4) * 64;
    int e0  = (b2 & 15) * 64;
#pragma unroll
    for (int r = 0; r < 16; ++r) {
      int hdL = ty + r * 4;
      t[hdL][tx] = Wo[(size_t)(hd0 + hdL) * 1024 + e0 + tx];
    }
    __syncthreads();
#pragma unroll
    for (int r = 0; r < 16; ++r) {
      int eL = ty + r * 4;
      Wot[(size_t)(e0 + eL) * 1024 + hd0 + tx] = (__bf16)t[tx][eL];
    }
  }
}

// ------- 8-phase GEMM, BM=128 for 2 blocks/CU: C = A @ Bt^T + bias ----------
// (R6-proven.) BM=128 x BN (192 MODE1 | 128 MODE0), BK=64, K=1024.
// 512 thr = 8 waves (2M x 4N); per-wave 64 x BN/4; acc[4][NB] f32x4.
// LDS/block = 80 KB (NB3) / 64 KB (NB2) -> 2 independent blocks per CU.

template <int MODE, int BN, int NDIM>
__global__ __launch_bounds__(512, 4) void gemm8h(const __bf16* __restrict__ A,
                                                 const __bf16* __restrict__ Bt,
                                                 const float* __restrict__ bias,
                                                 void* __restrict__ Cout,
                                                 __bf16* __restrict__ VT) {
  constexpr int K = 1024;
  constexpr int NB = BN / 64;            // B sub-tiles (and N frags per wave)
  constexpr int WC = BN / 4;             // per-wave col span
  __shared__ __attribute__((aligned(16))) __bf16 As[2 * 128 * 64];
  __shared__ __attribute__((aligned(16))) __bf16 Bs[2 * BN * 64];

  int tid = threadIdx.x, wave = tid >> 6, lane = tid & 63;
  int quad = lane >> 4, cc = lane & 15;
  constexpr int nb = NDIM / BN;
  int nwg = (int)gridDim.x;
  int bid = (int)blockIdx.x;
  bid = (bid & 7) * (nwg >> 3) + (bid >> 3);   // XCD-bijective (nwg%8==0)
  int bm = bid / nb, bn = bid % nb;
  const __bf16* Abase = A + (size_t)bm * 128 * K;
  const __bf16* Bbase = Bt + (size_t)bn * BN * K;
  int wrow = (wave >> 2) * 64;
  int wcol = (wave & 3) * WC;

  f32x4 acc[4][NB];
#pragma unroll
  for (int m = 0; m < 4; ++m)
#pragma unroll
    for (int n = 0; n < NB; ++n) acc[m][n] = (f32x4){0.f, 0.f, 0.f, 0.f};

  int srl = tid >> 3;                    // staging row 0..63
  int sch = tid & 7;
  int scol = (sch ^ (srl & 7)) * 8;      // pre-swizzled source col

#define STAGE_A(t, sub, buf)                                                   \
  load_lds16(Abase + (size_t)((sub) * 64 + srl) * K + (t) * 64 + scol,         \
             &As[(buf) * 8192 + (sub) * 4096 + tid * 8])
#define STAGE_B(t, sub, buf)                                                   \
  load_lds16(Bbase + (size_t)((sub) * 64 + srl) * K + (t) * 64 + scol,         \
             &Bs[(buf) * (BN * 64) + (sub) * 4096 + tid * 8])

  // prologue: tile0 full (2+NB), tile1 A pair; vmcnt(2) -> tile0 landed
#pragma unroll
  for (int s = 0; s < 2; ++s) STAGE_A(0, s, 0);
#pragma unroll
  for (int s = 0; s < NB; ++s) STAGE_B(0, s, 0);
#pragma unroll
  for (int s = 0; s < 2; ++s) STAGE_A(1, s, 1);
  asm volatile("s_waitcnt vmcnt(2)" ::: "memory");
  __builtin_amdgcn_sched_barrier(0);
  asm volatile("s_barrier" ::: "memory");

  bf16x8 af[4][2], bfr[NB][2];

#define RD_B(buf)                                                              \
  _Pragma("unroll") for (int n = 0; n < NB; ++n)                               \
      _Pragma("unroll") for (int kk = 0; kk < 2; ++kk)                         \
          bfr[n][kk] = *(const bf16x8*)&Bs[(buf) * (BN * 64) +                 \
                                           swz(wcol + n * 16 + cc, kk * 4 + quad)]
#define RD_A2(buf, mlo)                                                        \
  _Pragma("unroll") for (int m = mlo; m < (mlo) + 2; ++m)                      \
      _Pragma("unroll") for (int kk = 0; kk < 2; ++kk)                         \
          af[m][kk] = *(const bf16x8*)&As[(buf) * 8192 +                       \
                                          swz(wrow + m * 16 + cc, kk * 4 + quad)]
#define MFMA_M(m)                                                              \
  do {                                                                         \
    __builtin_amdgcn_s_setprio(1);                                             \
    _Pragma("unroll") for (int n = 0; n < NB; ++n)                             \
        _Pragma("unroll") for (int kk = 0; kk < 2; ++kk)                       \
            acc[m][n] = mfma16(af[m][kk], bfr[n][kk], acc[m][n]);              \
    __builtin_amdgcn_s_setprio(0);                                             \
  } while (0)
#define LGKM0                                                                  \
  asm volatile("s_waitcnt lgkmcnt(0)" ::: "memory");                           \
  __builtin_amdgcn_sched_barrier(0)
#define VMC2                                                                   \
  asm volatile("s_waitcnt vmcnt(2)" ::: "memory");                             \
  __builtin_amdgcn_sched_barrier(0)
#define BAR asm volatile("s_barrier" ::: "memory")

#pragma unroll 1
  for (int it = 0; it < 8; ++it) {
    int b_t = 2 * it + 1;
    int c_t = (2 * it + 2) & 15;         // clamped: dead restage on last iter
    int d_t = (2 * it + 3) & 15;
    // ---- tile a (buf0) ----
    RD_B(0); RD_A2(0, 0);
    STAGE_B(b_t, 0, 1); STAGE_B(b_t, 1, 1);
    LGKM0; MFMA_M(0); BAR;
    RD_A2(0, 2);
    if (NB >= 3) STAGE_B(b_t, 2, 1);
    LGKM0; MFMA_M(1); BAR;
    STAGE_A(c_t, 0, 0); STAGE_A(c_t, 1, 0);
    MFMA_M(2); BAR;
    MFMA_M(3);
    VMC2; BAR;
    // ---- tile b (buf1) ----
    RD_B(1); RD_A2(1, 0);
    STAGE_B(c_t, 0, 0); STAGE_B(c_t, 1, 0);
    LGKM0; MFMA_M(0); BAR;
    RD_A2(1, 2);
    if (NB >= 3) STAGE_B(c_t, 2, 0);
    LGKM0; MFMA_M(1); BAR;
    STAGE_A(d_t, 0, 1); STAGE_A(d_t, 1, 1);
    MFMA_M(2); BAR;
    MFMA_M(3);
    VMC2; BAR;
  }
  asm volatile("s_waitcnt vmcnt(0)" ::: "memory");  // drain dead restages

  // epilogue — plain cached stores (nt falsified in R5)
#pragma unroll
  for (int n = 0; n < NB; ++n) {
    int gcol = bn * BN + wcol + n * 16 + cc;
    float bv = bias[gcol];
#pragma unroll
    for (int m = 0; m < 4; ++m) {
      int grow0 = bm * 128 + wrow + m * 16 + quad * 4;
      if (MODE == 0) {
#pragma unroll
        for (int r = 0; r < 4; ++r)
          ((float*)Cout)[(size_t)(grow0 + r) * NDIM + gcol] = acc[m][n][r] + bv;
      } else if (gcol < 2048) {          // Q|K -> QKb (stride 2048), Q scaled
        float sc = (gcol < 1024) ? SCORE_SCALE : 1.0f;
#pragma unroll
        for (int r = 0; r < 4; ++r)
          ((__bf16*)Cout)[(size_t)(grow0 + r) * 2048 + gcol] =
              (__bf16)((acc[m][n][r] + bv) * sc);
      } else {                           // V -> VT[(b*16+h)*64+d][s], packed x4
        int bh = (grow0 >> 11) * 16 + ((gcol >> 6) & 15);
        int d  = gcol & 63;
        bf16x4 pk;
#pragma unroll
        for (int r = 0; r < 4; ++r) pk[r] = (__bf16)(acc[m][n][r] + bv);
        *(bf16x4*)&VT[((size_t)(bh * 64 + d)) * 2048 + (grow0 & 2047)] = pk;
      }
    }
  }
#undef STAGE_A
#undef STAGE_B
#undef RD_B
#undef RD_A2
#undef MFMA_M
#undef LGKM0
#undef VMC2
#undef BAR
}

// ---------------- causal flash attention (R6 structure + counted vmcnt) -----
// Q-tile 128, 256 threads (4 waves x 32 q-rows), KV 64 double-buffered.
// QKb [B*S][2048] = Q|K (Q pre-scaled); V from VT [bh][64 d][2048 s].
// S^T trick -> P store is one ds_write_b64 per (i,j). Ps overlays Qs.
// LDS 48K -> 3 blocks/CU; grid 1024 = 768 resident + 256 refill queue.
// CHANGE vs R6: the per-tile __syncthreads() (vmcnt(0) drain — waits the
// JUST-ISSUED t+1 prefetch!) is replaced by T4 counted sync:
//   issue t+1; vmcnt(2) [only tile t's loads, issued a full iter ago];
//   s_barrier; compute t; s_barrier [protects buf restaged next iter].
// Prefetch now stays in flight across the barrier (m97-drain fix).

__global__ __launch_bounds__(256, 3) void attn(const __bf16* __restrict__ QKb,
                                               const __bf16* __restrict__ VT,
                                               __bf16* __restrict__ O) {
  int bx = blockIdx.x;
  int bh = bx & 63;
  int g  = bx >> 6;                           // 0..15
  int qt = (g < 8) ? (15 - g) : (g - 8);
  int h  = bh & 15;
  int b  = bh >> 4;
  int q0 = qt * 128;
  int tid = threadIdx.x, wave = tid >> 6, lane = tid & 63;
  int quad = lane >> 4, c = lane & 15;

  // 48 KB: Qs 16K (reused as per-wave Ps) | Ks 2x8K | Vs 2x8K
  __shared__ __attribute__((aligned(16))) __bf16 smem[24576];
  __bf16* Qs = smem;                         // 128*64
  __bf16* Ks = smem + 8192;                  // 2 * 64*64
  __bf16* Vs = smem + 16384;                 // 2 * 64*64 (V^T tiles [d][kv])
  __bf16* Ps = smem + wave * 2048;           // own wave's Q rows (dead after prologue)

  const __bf16* Qbase = QKb + (size_t)(b * S_ + q0) * 2048 + h * 64;
  const __bf16* Vbase = VT + (size_t)bh * (64 * 2048);
#pragma unroll
  for (int p = 0; p < 4; ++p) {
    int gi = tid + p * 256;           // 0..1023
    int row = gi >> 3, pch = gi & 7;
    load_lds16(Qbase + (size_t)row * 2048 + (pch ^ (row & 7)) * 8, &Qs[gi * 8]);
  }
  {
    const __bf16* Kb = QKb + (size_t)(b * S_) * 2048 + 1024 + h * 64;
#pragma unroll
    for (int p = 0; p < 2; ++p) {
      int gi = tid + p * 256;         // 0..511
      int row = gi >> 3, pch = gi & 7;
      load_lds16(Kb + (size_t)row * 2048 + (pch ^ (row & 7)) * 8, &Ks[gi * 8]);
      load_lds16(Vbase + (size_t)row * 2048 + (pch ^ (row & 7)) * 8, &Vs[gi * 8]);
    }
  }
  __syncthreads();                    // prologue full drain (once) — Q ready

  bf16x8 qf[2][2];
#pragma unroll
  for (int i = 0; i < 2; ++i)
#pragma unroll
    for (int kk = 0; kk < 2; ++kk)
      qf[i][kk] = *(const bf16x8*)&Qs[swz(wave * 32 + i * 16 + c, kk * 4 + quad)];

  const __bf16 one_b = (__bf16)1.0f;
  bf16x8 ones = { one_b, one_b, one_b, one_b, one_b, one_b, one_b, one_b };

  f32x4 acc_o[2][4], acc_l[2];
#pragma unroll
  for (int i = 0; i < 2; ++i) {
    acc_l[i] = (f32x4){0.f, 0.f, 0.f, 0.f};
#pragma unroll
    for (int j = 0; j < 4; ++j) acc_o[i][j] = (f32x4){0.f, 0.f, 0.f, 0.f};
  }

  int qwave = q0 + wave * 32;         // this wave's first q row
  int ntiles = qt * 2 + 2;
  for (int t = 0; t < ntiles; ++t) {
    int cur = t & 1;
    if (t + 1 < ntiles) {             // prefetch next KV tile (other buffer)
      int kv1 = (t + 1) * 64;
      const __bf16* Kb = QKb + (size_t)(b * S_ + kv1) * 2048 + 1024 + h * 64;
      const __bf16* Vb = Vbase + kv1;
#pragma unroll
      for (int p = 0; p < 2; ++p) {
        int gi = tid + p * 256;
        int row = gi >> 3, pch = gi & 7;
        load_lds16(Kb + (size_t)row * 2048 + (pch ^ (row & 7)) * 8,
                   &Ks[(cur ^ 1) * 4096 + gi * 8]);
        load_lds16(Vb + (size_t)row * 2048 + (pch ^ (row & 7)) * 8,
                   &Vs[(cur ^ 1) * 4096 + gi * 8]);
      }
      // wait ONLY tile t's 4 loads (issued last iter); t+1's 4 stay in flight
      asm volatile("s_waitcnt vmcnt(4)" ::: "memory");
    } else {
      asm volatile("s_waitcnt vmcnt(0)" ::: "memory");
    }
    __builtin_amdgcn_sched_barrier(0);
    asm volatile("s_barrier" ::: "memory");   // all waves' tile-t loads landed

    int kv0 = t * 64;
    if (kv0 <= qwave + 31) {          // wave has at least one unmasked row
      const __bf16* Kc = Ks + cur * 4096;
      const __bf16* Vc = Vs + cur * 4096;

      // S^T = K Q^T : rows=kv, cols=q  (log2-domain scores, Q pre-scaled)
      f32x4 acc_t[2][4];
#pragma unroll
      for (int i = 0; i < 2; ++i)
#pragma unroll
        for (int j = 0; j < 4; ++j) acc_t[i][j] = (f32x4){0.f, 0.f, 0.f, 0.f};
      bf16x8 kf[4][2];
#pragma unroll
      for (int j = 0; j < 4; ++j)
#pragma unroll
        for (int kk = 0; kk < 2; ++kk)
          kf[j][kk] = *(const bf16x8*)&Kc[swz(j * 16 + c, kk * 4 + quad)];
      __builtin_amdgcn_s_setprio(1);
#pragma unroll
      for (int i = 0; i < 2; ++i)
#pragma unroll
        for (int j = 0; j < 4; ++j)
#pragma unroll
          for (int kk = 0; kk < 2; ++kk)
            acc_t[i][j] = mfma16(kf[j][kk], qf[i][kk], acc_t[i][j]);
      __builtin_amdgcn_s_setprio(0);

      // p = exp2(s); mask only when this wave straddles the diagonal
      bool domask = (kv0 + 63 > qwave);
#pragma unroll
      for (int i = 0; i < 2; ++i) {
        int q_l = i * 16 + c;                      // wave-local q row
        int q_g = qwave + q_l;                     // global q row
#pragma unroll
        for (int j = 0; j < 4; ++j) {
          bf16x4 pk;
#pragma unroll
          for (int r = 0; r < 4; ++r) {
            float p = __builtin_amdgcn_exp2f(acc_t[i][j][r]);
            if (domask) {
              int kv = kv0 + j * 16 + quad * 4 + r;
              p = (kv > q_g) ? 0.f : p;
            }
            pk[r] = (__bf16)p;
          }
          int dch8 = j * 2 + (quad >> 1);
          int phys = q_l * 64 + ((dch8 ^ (q_l & 7)) * 8) + (quad & 1) * 4;
          *(bf16x4*)&Ps[phys] = pk;
        }
      }

      // PV + row-sum (ones-MFMA); same-wave LDS ops are in-order
      bf16x8 pf[2][2], vf[4][2];
#pragma unroll
      for (int i = 0; i < 2; ++i)
#pragma unroll
        for (int kk = 0; kk < 2; ++kk)
          pf[i][kk] = *(const bf16x8*)&Ps[swz(i * 16 + c, kk * 4 + quad)];
#pragma unroll
      for (int j = 0; j < 4; ++j)
#pragma unroll
        for (int kk = 0; kk < 2; ++kk)
          vf[j][kk] = *(const bf16x8*)&Vc[swz(j * 16 + c, kk * 4 + quad)];
      __builtin_amdgcn_s_setprio(1);
#pragma unroll
      for (int i = 0; i < 2; ++i) {
#pragma unroll
        for (int j = 0; j < 4; ++j)
#pragma unroll
          for (int kk = 0; kk < 2; ++kk)
            acc_o[i][j] = mfma16(pf[i][kk], vf[j][kk], acc_o[i][j]);
        acc_l[i] = mfma16(pf[i][0], ones, acc_l[i]);
        acc_l[i] = mfma16(pf[i][1], ones, acc_l[i]);
      }
      __builtin_amdgcn_s_setprio(0);
    }

    // plain barrier (no drain): all waves done reading buf (cur) before the
    // next iteration restages it; t+1 prefetch remains in flight.
    asm volatile("s_barrier" ::: "memory");
  }

  __bf16* Obase = O + (size_t)(b * S_ + q0) * 1024 + h * 64;
#pragma unroll
  for (int i = 0; i < 2; ++i)
#pragma unroll
    for (int r = 0; r < 4; ++r) {
      float rl = 1.0f / acc_l[i][r];
      int row = wave * 32 + i * 16 + quad * 4 + r;
#pragma unroll
      for (int j = 0; j < 4; ++j)
        Obase[(size_t)row * 1024 + j * 16 + c] = (__bf16)(acc_o[i][j][r] * rl);
    }
}

// ---------------- launcher ----------------

extern "C" void kernel_launch(void* const* d_in, const int* in_sizes, int n_in,
                              void* d_out, int out_size, void* d_ws, size_t ws_size,
                              hipStream_t stream) {
  (void)in_sizes; (void)n_in; (void)out_size; (void)ws_size;
  const float* x  = (const float*)d_in[0];
  const float* Wq = (const float*)d_in[1];
  const float* bq = (const float*)d_in[2];
  const float* Wk = (const float*)d_in[3];
  const float* bk = (const float*)d_in[4];
  const float* Wv = (const float*)d_in[5];
  const float* bv = (const float*)d_in[6];
  const float* Wo = (const float*)d_in[7];
  const float* bo = (const float*)d_in[8];

  char* w = (char*)d_ws;
  __bf16* xb   = (__bf16*)(w);                         // 16 MB
  __bf16* Wt   = (__bf16*)(w + (16ull << 20));         //  6 MB
  __bf16* Wot  = (__bf16*)(w + (22ull << 20));         //  2 MB
  float*  bqkv = (float*) (w + (24ull << 20));         // 12 KB
  __bf16* QKb  = (__bf16*)(w + (25ull << 20));         // 32 MB (Q|K, stride 2048)
  __bf16* Ob   = (__bf16*)(w + (57ull << 20));         // 16 MB
  __bf16* VT   = (__bf16*)(w + (73ull << 20));         // 16 MB (total 89 MB)

  prep<<<9216, 256, 0, stream>>>((const float4*)x, Wq, Wk, Wv, bq, bk, bv, Wo,
                                 xb, Wt, bqkv, Wot);
  gemm8h<1, 192, 3072><<<1024, 512, 0, stream>>>(xb, Wt, bqkv, (void*)QKb, VT);
  attn<<<1024, 256, 0, stream>>>(QKb, VT, Ob);
  gemm8h<0, 128, 1024><<<512, 512, 0, stream>>>(Ob, Wot, bo, d_out, nullptr);
}

// Round 9
// 234.561 us; speedup vs baseline: 1.0710x; 1.0464x over previous
//
#include <hip/hip_runtime.h>

typedef __bf16 bf16x8 __attribute__((ext_vector_type(8)));
typedef __bf16 bf16x4 __attribute__((ext_vector_type(4)));
typedef float  f32x4  __attribute__((ext_vector_type(4)));

#define B_    4
#define S_    2048
#define E_    1024
#define H_    16
#define D_    64
#define MROWS (B_*S_)   // 8192

// log2(e) / sqrt(D) — folded into Q in the GEMM epilogue
#define SCORE_SCALE 0.18033688011112043f

__device__ __forceinline__ void load_lds16(const void* g, void* l) {
  __builtin_amdgcn_global_load_lds((__attribute__((address_space(1))) void*)g,
                                   (__attribute__((address_space(3))) void*)l,
                                   16, 0, 0);
}

__device__ __forceinline__ f32x4 mfma16(bf16x8 a, bf16x8 b, f32x4 c) {
  return __builtin_amdgcn_mfma_f32_16x16x32_bf16(a, b, c, 0, 0, 0);
}

// swizzled LDS element offset, 64-col bf16 rows: data chunk (8 elems) lands at
// physical chunk (dchunk ^ (row&7))  -> all fragment reads are <=2-way (free)
__device__ __forceinline__ int swz(int row, int dchunk) {
  return row * 64 + ((dchunk ^ (row & 7)) * 8);
}

// ---------------- fused prep: cvt_x | pack_w | pack_wo ----------------

__global__ void prep(const float4* __restrict__ x, const float* __restrict__ Wq,
                     const float* __restrict__ Wk, const float* __restrict__ Wv,
                     const float* __restrict__ bq, const float* __restrict__ bk,
                     const float* __restrict__ bv, const float* __restrict__ Wo,
                     __bf16* __restrict__ xb, __bf16* __restrict__ Wt,
                     float* __restrict__ bqkv, __bf16* __restrict__ Wot) {
  __shared__ float t[64][65];
  int bid = blockIdx.x;
  if (bid < 8192) {                      // cvt_x: fp32 x -> bf16
    int id = bid * 256 + threadIdx.x;
    float4 v = x[id];
    bf16x4 o = { (__bf16)v.x, (__bf16)v.y, (__bf16)v.z, (__bf16)v.w };
    *(bf16x4*)(xb + 4 * (size_t)id) = o;
    return;
  }
  int tx = threadIdx.x & 63;
  int ty = threadIdx.x >> 6;
  if (bid < 8960) {                      // pack_w: [H,E,D] -> Wt[3*H*D][E]
    int b2 = bid - 8192;                 // 768
    int e0 = (b2 & 15) * 64;
    int h  = (b2 >> 4) & 15;
    int p  = b2 >> 8;
    const float* W    = (p == 0) ? Wq : (p == 1) ? Wk : Wv;
    const float* bsrc = (p == 0) ? bq : (p == 1) ? bk : bv;
#pragma unroll
    for (int r = 0; r < 16; ++r) {
      int eL = ty + r * 4;
      t[eL][tx] = W[((size_t)h * 1024 + (e0 + eL)) * 64 + tx];
    }
    __syncthreads();
#pragma unroll
    for (int r = 0; r < 16; ++r) {
      int d = ty + r * 4;
      Wt[((size_t)(p * 1024 + h * 64 + d)) * 1024 + e0 + tx] = (__bf16)t[tx][d];
    }
    if ((b2 & 15) == 0 && threadIdx.x < 64)
      bqkv[p * 1024 + h * 64 + threadIdx.x] = bsrc[h * 64 + threadIdx.x];
  } else {                               // pack_wo: Wo[1024,1024] -> Wot[e][hd]
    int b2 = bid - 8960;                 // 256
    int hd0 = (b2 >> 4) * 64;
    int e0  = (b2 & 15) * 64;
#pragma unroll
    for (int r = 0; r < 16; ++r) {
      int hdL = ty + r * 4;
      t[hdL][tx] = Wo[(size_t)(hd0 + hdL) * 1024 + e0 + tx];
    }
    __syncthreads();
#pragma unroll
    for (int r = 0; r < 16; ++r) {
      int eL = ty + r * 4;
      Wot[(size_t)(e0 + eL) * 1024 + hd0 + tx] = (__bf16)t[tx][eL];
    }
  }
}

// ------- 8-phase GEMM, BM=128 for 2 blocks/CU: C = A @ Bt^T + bias ----------
// (R6-proven.) BM=128 x BN (192 MODE1 | 128 MODE0), BK=64, K=1024.
// 512 thr = 8 waves (2M x 4N); per-wave 64 x BN/4; acc[4][NB] f32x4.
// LDS/block = 80 KB (NB3) / 64 KB (NB2) -> 2 independent blocks per CU.

template <int MODE, int BN, int NDIM>
__global__ __launch_bounds__(512, 4) void gemm8h(const __bf16* __restrict__ A,
                                                 const __bf16* __restrict__ Bt,
                                                 const float* __restrict__ bias,
                                                 void* __restrict__ Cout,
                                                 __bf16* __restrict__ VT) {
  constexpr int K = 1024;
  constexpr int NB = BN / 64;            // B sub-tiles (and N frags per wave)
  constexpr int WC = BN / 4;             // per-wave col span
  __shared__ __attribute__((aligned(16))) __bf16 As[2 * 128 * 64];
  __shared__ __attribute__((aligned(16))) __bf16 Bs[2 * BN * 64];

  int tid = threadIdx.x, wave = tid >> 6, lane = tid & 63;
  int quad = lane >> 4, cc = lane & 15;
  constexpr int nb = NDIM / BN;
  int nwg = (int)gridDim.x;
  int bid = (int)blockIdx.x;
  bid = (bid & 7) * (nwg >> 3) + (bid >> 3);   // XCD-bijective (nwg%8==0)
  int bm = bid / nb, bn = bid % nb;
  const __bf16* Abase = A + (size_t)bm * 128 * K;
  const __bf16* Bbase = Bt + (size_t)bn * BN * K;
  int wrow = (wave >> 2) * 64;
  int wcol = (wave & 3) * WC;

  f32x4 acc[4][NB];
#pragma unroll
  for (int m = 0; m < 4; ++m)
#pragma unroll
    for (int n = 0; n < NB; ++n) acc[m][n] = (f32x4){0.f, 0.f, 0.f, 0.f};

  int srl = tid >> 3;                    // staging row 0..63
  int sch = tid & 7;
  int scol = (sch ^ (srl & 7)) * 8;      // pre-swizzled source col

#define STAGE_A(t, sub, buf)                                                   \
  load_lds16(Abase + (size_t)((sub) * 64 + srl) * K + (t) * 64 + scol,         \
             &As[(buf) * 8192 + (sub) * 4096 + tid * 8])
#define STAGE_B(t, sub, buf)                                                   \
  load_lds16(Bbase + (size_t)((sub) * 64 + srl) * K + (t) * 64 + scol,         \
             &Bs[(buf) * (BN * 64) + (sub) * 4096 + tid * 8])

  // prologue: tile0 full (2+NB), tile1 A pair; vmcnt(2) -> tile0 landed
#pragma unroll
  for (int s = 0; s < 2; ++s) STAGE_A(0, s, 0);
#pragma unroll
  for (int s = 0; s < NB; ++s) STAGE_B(0, s, 0);
#pragma unroll
  for (int s = 0; s < 2; ++s) STAGE_A(1, s, 1);
  asm volatile("s_waitcnt vmcnt(2)" ::: "memory");
  __builtin_amdgcn_sched_barrier(0);
  asm volatile("s_barrier" ::: "memory");

  bf16x8 af[4][2], bfr[NB][2];

#define RD_B(buf)                                                              \
  _Pragma("unroll") for (int n = 0; n < NB; ++n)                               \
      _Pragma("unroll") for (int kk = 0; kk < 2; ++kk)                         \
          bfr[n][kk] = *(const bf16x8*)&Bs[(buf) * (BN * 64) +                 \
                                           swz(wcol + n * 16 + cc, kk * 4 + quad)]
#define RD_A2(buf, mlo)                                                        \
  _Pragma("unroll") for (int m = mlo; m < (mlo) + 2; ++m)                      \
      _Pragma("unroll") for (int kk = 0; kk < 2; ++kk)                         \
          af[m][kk] = *(const bf16x8*)&As[(buf) * 8192 +                       \
                                          swz(wrow + m * 16 + cc, kk * 4 + quad)]
#define MFMA_M(m)                                                              \
  do {                                                                         \
    __builtin_amdgcn_s_setprio(1);                                             \
    _Pragma("unroll") for (int n = 0; n < NB; ++n)                             \
        _Pragma("unroll") for (int kk = 0; kk < 2; ++kk)                       \
            acc[m][n] = mfma16(af[m][kk], bfr[n][kk], acc[m][n]);              \
    __builtin_amdgcn_s_setprio(0);                                             \
  } while (0)
#define LGKM0                                                                  \
  asm volatile("s_waitcnt lgkmcnt(0)" ::: "memory");                           \
  __builtin_amdgcn_sched_barrier(0)
#define VMC2                                                                   \
  asm volatile("s_waitcnt vmcnt(2)" ::: "memory");                             \
  __builtin_amdgcn_sched_barrier(0)
#define BAR asm volatile("s_barrier" ::: "memory")

#pragma unroll 1
  for (int it = 0; it < 8; ++it) {
    int b_t = 2 * it + 1;
    int c_t = (2 * it + 2) & 15;         // clamped: dead restage on last iter
    int d_t = (2 * it + 3) & 15;
    // ---- tile a (buf0) ----
    RD_B(0); RD_A2(0, 0);
    STAGE_B(b_t, 0, 1); STAGE_B(b_t, 1, 1);
    LGKM0; MFMA_M(0); BAR;
    RD_A2(0, 2);
    if (NB >= 3) STAGE_B(b_t, 2, 1);
    LGKM0; MFMA_M(1); BAR;
    STAGE_A(c_t, 0, 0); STAGE_A(c_t, 1, 0);
    MFMA_M(2); BAR;
    MFMA_M(3);
    VMC2; BAR;
    // ---- tile b (buf1) ----
    RD_B(1); RD_A2(1, 0);
    STAGE_B(c_t, 0, 0); STAGE_B(c_t, 1, 0);
    LGKM0; MFMA_M(0); BAR;
    RD_A2(1, 2);
    if (NB >= 3) STAGE_B(c_t, 2, 0);
    LGKM0; MFMA_M(1); BAR;
    STAGE_A(d_t, 0, 1); STAGE_A(d_t, 1, 1);
    MFMA_M(2); BAR;
    MFMA_M(3);
    VMC2; BAR;
  }
  asm volatile("s_waitcnt vmcnt(0)" ::: "memory");  // drain dead restages

  // epilogue — plain cached stores (nt falsified in R5)
#pragma unroll
  for (int n = 0; n < NB; ++n) {
    int gcol = bn * BN + wcol + n * 16 + cc;
    float bv = bias[gcol];
#pragma unroll
    for (int m = 0; m < 4; ++m) {
      int grow0 = bm * 128 + wrow + m * 16 + quad * 4;
      if (MODE == 0) {
#pragma unroll
        for (int r = 0; r < 4; ++r)
          ((float*)Cout)[(size_t)(grow0 + r) * NDIM + gcol] = acc[m][n][r] + bv;
      } else if (gcol < 2048) {          // Q|K -> QKb (stride 2048), Q scaled
        float sc = (gcol < 1024) ? SCORE_SCALE : 1.0f;
#pragma unroll
        for (int r = 0; r < 4; ++r)
          ((__bf16*)Cout)[(size_t)(grow0 + r) * 2048 + gcol] =
              (__bf16)((acc[m][n][r] + bv) * sc);
      } else {                           // V -> VT[(b*16+h)*64+d][s], packed x4
        int bh = (grow0 >> 11) * 16 + ((gcol >> 6) & 15);
        int d  = gcol & 63;
        bf16x4 pk;
#pragma unroll
        for (int r = 0; r < 4; ++r) pk[r] = (__bf16)(acc[m][n][r] + bv);
        *(bf16x4*)&VT[((size_t)(bh * 64 + d)) * 2048 + (grow0 & 2047)] = pk;
      }
    }
  }
#undef STAGE_A
#undef STAGE_B
#undef RD_B
#undef RD_A2
#undef MFMA_M
#undef LGKM0
#undef VMC2
#undef BAR
}

// ---------------- causal flash attention — 40KB LDS, 4 blocks/CU ------------
// Q-tile 128, 256 threads (4 waves x 32 q-rows), KV 64 double-buffered.
// QKb [B*S][2048] = Q|K (Q pre-scaled); V from VT [bh][64 d][2048 s].
// CHANGES vs R8 (loop/sync structure untouched):
//  * qf loaded DIRECT from global (one-time, 4x16B/thread) — Qs staging
//    (16KB transient LDS) deleted.
//  * P round-trip split by i-half: write 4x b64 for i, read its 2x b128
//    immediately (same-wave LDS ops are in-order) -> Ps = 2KB/wave, 8KB total.
// LDS 40KB = Ps 8K | Ks 2x8K | Vs 2x8K -> 4 blocks/CU, 16 waves/CU.
// Grid 1024 all-resident; co-resident blocks b,b+256,b+512,b+768 have
// qt sets {15-a,11-a,a,4+a} (sum 30) -> per-CU work constant, zero tail.

__global__ __launch_bounds__(256, 4) void attn(const __bf16* __restrict__ QKb,
                                               const __bf16* __restrict__ VT,
                                               __bf16* __restrict__ O) {
  int bx = blockIdx.x;
  int bh = bx & 63;
  int g  = bx >> 6;                           // 0..15
  int qt = (g < 8) ? (15 - g) : (g - 8);
  int h  = bh & 15;
  int b  = bh >> 4;
  int q0 = qt * 128;
  int tid = threadIdx.x, wave = tid >> 6, lane = tid & 63;
  int quad = lane >> 4, c = lane & 15;

  // 40 KB: Ps 4x2K | Ks 2x8K | Vs 2x8K
  __shared__ __attribute__((aligned(16))) __bf16 smem[20480];
  __bf16* Ps = smem + wave * 1024;           // own wave's 16 q-rows x 64 kv
  __bf16* Ks = smem + 4096;                  // 2 * 64*64
  __bf16* Vs = smem + 12288;                 // 2 * 64*64 (V^T tiles [d][kv])

  const __bf16* Vbase = VT + (size_t)bh * (64 * 2048);
  int qwave = q0 + wave * 32;         // this wave's first q row

  // qf direct from global: qf[i][kk] = Q[qwave+i*16+c][(kk*4+quad)*8 ..+8]
  bf16x8 qf[2][2];
#pragma unroll
  for (int i = 0; i < 2; ++i)
#pragma unroll
    for (int kk = 0; kk < 2; ++kk)
      qf[i][kk] = *(const bf16x8*)&QKb[(size_t)(b * S_ + qwave + i * 16 + c) * 2048 +
                                       h * 64 + (kk * 4 + quad) * 8];

  {
    const __bf16* Kb = QKb + (size_t)(b * S_) * 2048 + 1024 + h * 64;
#pragma unroll
    for (int p = 0; p < 2; ++p) {
      int gi = tid + p * 256;         // 0..511
      int row = gi >> 3, pch = gi & 7;
      load_lds16(Kb + (size_t)row * 2048 + (pch ^ (row & 7)) * 8, &Ks[gi * 8]);
      load_lds16(Vbase + (size_t)row * 2048 + (pch ^ (row & 7)) * 8, &Vs[gi * 8]);
    }
  }
  __syncthreads();                    // prologue full drain (once) — K/V(0) ready

  const __bf16 one_b = (__bf16)1.0f;
  bf16x8 ones = { one_b, one_b, one_b, one_b, one_b, one_b, one_b, one_b };

  f32x4 acc_o[2][4], acc_l[2];
#pragma unroll
  for (int i = 0; i < 2; ++i) {
    acc_l[i] = (f32x4){0.f, 0.f, 0.f, 0.f};
#pragma unroll
    for (int j = 0; j < 4; ++j) acc_o[i][j] = (f32x4){0.f, 0.f, 0.f, 0.f};
  }

  int ntiles = qt * 2 + 2;
  for (int t = 0; t < ntiles; ++t) {
    int cur = t & 1;
    if (t + 1 < ntiles) {             // prefetch next KV tile (other buffer)
      int kv1 = (t + 1) * 64;
      const __bf16* Kb = QKb + (size_t)(b * S_ + kv1) * 2048 + 1024 + h * 64;
      const __bf16* Vb = Vbase + kv1;
#pragma unroll
      for (int p = 0; p < 2; ++p) {
        int gi = tid + p * 256;
        int row = gi >> 3, pch = gi & 7;
        load_lds16(Kb + (size_t)row * 2048 + (pch ^ (row & 7)) * 8,
                   &Ks[(cur ^ 1) * 4096 + gi * 8]);
        load_lds16(Vb + (size_t)row * 2048 + (pch ^ (row & 7)) * 8,
                   &Vs[(cur ^ 1) * 4096 + gi * 8]);
      }
      // wait ONLY tile t's 4 loads (issued last iter); t+1's 4 stay in flight
      asm volatile("s_waitcnt vmcnt(4)" ::: "memory");
    } else {
      asm volatile("s_waitcnt vmcnt(0)" ::: "memory");
    }
    __builtin_amdgcn_sched_barrier(0);
    asm volatile("s_barrier" ::: "memory");   // all waves' tile-t loads landed

    int kv0 = t * 64;
    if (kv0 <= qwave + 31) {          // wave has at least one unmasked row
      const __bf16* Kc = Ks + cur * 4096;
      const __bf16* Vc = Vs + cur * 4096;

      // S^T = K Q^T : rows=kv, cols=q  (log2-domain scores, Q pre-scaled)
      f32x4 acc_t[2][4];
#pragma unroll
      for (int i = 0; i < 2; ++i)
#pragma unroll
        for (int j = 0; j < 4; ++j) acc_t[i][j] = (f32x4){0.f, 0.f, 0.f, 0.f};
      bf16x8 kf[4][2];
#pragma unroll
      for (int j = 0; j < 4; ++j)
#pragma unroll
        for (int kk = 0; kk < 2; ++kk)
          kf[j][kk] = *(const bf16x8*)&Kc[swz(j * 16 + c, kk * 4 + quad)];
      __builtin_amdgcn_s_setprio(1);
#pragma unroll
      for (int i = 0; i < 2; ++i)
#pragma unroll
        for (int j = 0; j < 4; ++j)
#pragma unroll
          for (int kk = 0; kk < 2; ++kk)
            acc_t[i][j] = mfma16(kf[j][kk], qf[i][kk], acc_t[i][j]);
      __builtin_amdgcn_s_setprio(0);

      // p = exp2(s); Ps holds ONE i-half (16 rows x 64) per wave: write the
      // half's 4x b64 then immediately read its pf (same-wave LDS in-order).
      bool domask = (kv0 + 63 > qwave);
      bf16x8 pf[2][2];
#pragma unroll
      for (int i = 0; i < 2; ++i) {
        int q_g = qwave + i * 16 + c;              // global q row
#pragma unroll
        for (int j = 0; j < 4; ++j) {
          bf16x4 pk;
#pragma unroll
          for (int r = 0; r < 4; ++r) {
            float p = __builtin_amdgcn_exp2f(acc_t[i][j][r]);
            if (domask) {
              int kv = kv0 + j * 16 + quad * 4 + r;
              p = (kv > q_g) ? 0.f : p;
            }
            pk[r] = (__bf16)p;
          }
          int dch8 = j * 2 + (quad >> 1);
          int phys = c * 64 + ((dch8 ^ (c & 7)) * 8) + (quad & 1) * 4;
          *(bf16x4*)&Ps[phys] = pk;
        }
#pragma unroll
        for (int kk = 0; kk < 2; ++kk)
          pf[i][kk] = *(const bf16x8*)&Ps[swz(c, kk * 4 + quad)];
      }

      // PV + row-sum (ones-MFMA)
      bf16x8 vf[4][2];
#pragma unroll
      for (int j = 0; j < 4; ++j)
#pragma unroll
        for (int kk = 0; kk < 2; ++kk)
          vf[j][kk] = *(const bf16x8*)&Vc[swz(j * 16 + c, kk * 4 + quad)];
      __builtin_amdgcn_s_setprio(1);
#pragma unroll
      for (int i = 0; i < 2; ++i) {
#pragma unroll
        for (int j = 0; j < 4; ++j)
#pragma unroll
          for (int kk = 0; kk < 2; ++kk)
            acc_o[i][j] = mfma16(pf[i][kk], vf[j][kk], acc_o[i][j]);
        acc_l[i] = mfma16(pf[i][0], ones, acc_l[i]);
        acc_l[i] = mfma16(pf[i][1], ones, acc_l[i]);
      }
      __builtin_amdgcn_s_setprio(0);
    }

    // plain barrier (no drain): all waves done reading buf (cur) before the
    // next iteration restages it; t+1 prefetch remains in flight.
    asm volatile("s_barrier" ::: "memory");
  }

  __bf16* Obase = O + (size_t)(b * S_ + q0) * 1024 + h * 64;
#pragma unroll
  for (int i = 0; i < 2; ++i)
#pragma unroll
    for (int r = 0; r < 4; ++r) {
      float rl = 1.0f / acc_l[i][r];
      int row = wave * 32 + i * 16 + quad * 4 + r;
#pragma unroll
      for (int j = 0; j < 4; ++j)
        Obase[(size_t)row * 1024 + j * 16 + c] = (__bf16)(acc_o[i][j][r] * rl);
    }
}

// ---------------- launcher ----------------

extern "C" void kernel_launch(void* const* d_in, const int* in_sizes, int n_in,
                              void* d_out, int out_size, void* d_ws, size_t ws_size,
                              hipStream_t stream) {
  (void)in_sizes; (void)n_in; (void)out_size; (void)ws_size;
  const float* x  = (const float*)d_in[0];
  const float* Wq = (const float*)d_in[1];
  const float* bq = (const float*)d_in[2];
  const float* Wk = (const float*)d_in[3];
  const float* bk = (const float*)d_in[4];
  const float* Wv = (const float*)d_in[5];
  const float* bv = (const float*)d_in[6];
  const float* Wo = (const float*)d_in[7];
  const float* bo = (const float*)d_in[8];

  char* w = (char*)d_ws;
  __bf16* xb   = (__bf16*)(w);                         // 16 MB
  __bf16* Wt   = (__bf16*)(w + (16ull << 20));         //  6 MB
  __bf16* Wot  = (__bf16*)(w + (22ull << 20));         //  2 MB
  float*  bqkv = (float*) (w + (24ull << 20));         // 12 KB
  __bf16* QKb  = (__bf16*)(w + (25ull << 20));         // 32 MB (Q|K, stride 2048)
  __bf16* Ob   = (__bf16*)(w + (57ull << 20));         // 16 MB
  __bf16* VT   = (__bf16*)(w + (73ull << 20));         // 16 MB (total 89 MB)

  prep<<<9216, 256, 0, stream>>>((const float4*)x, Wq, Wk, Wv, bq, bk, bv, Wo,
                                 xb, Wt, bqkv, Wot);
  gemm8h<1, 192, 3072><<<1024, 512, 0, stream>>>(xb, Wt, bqkv, (void*)QKb, VT);
  attn<<<1024, 256, 0, stream>>>(QKb, VT, Ob);
  gemm8h<0, 128, 1024><<<512, 512, 0, stream>>>(Ob, Wot, bo, d_out, nullptr);
}